// Round 7
// baseline (46.020 us; speedup 1.0000x reference)
//
#include <hip/hip_runtime.h>
#include <math.h>

#define NN 512
#define DD 512
#define HH 1024
#define C2LOG2E 2.8853900817779268f   // 2*log2(e): exp(2y) = exp2(C*y)

typedef __attribute__((ext_vector_type(8))) short bf16x8;
typedef __attribute__((ext_vector_type(4))) float f32x4;
typedef __attribute__((ext_vector_type(2))) float f32x2;

static __device__ __forceinline__ float rcp_fast(float x) {
    return __builtin_amdgcn_rcpf(x);   // v_rcp_f32
}
static __device__ __forceinline__ float exp2_fast(float x) {
    return __builtin_amdgcn_exp2f(x);  // v_exp_f32
}
static __device__ __forceinline__ ushort f2bf(float f) {   // RNE f32->bf16
    unsigned u = __float_as_uint(f);
    u += 0x7FFF + ((u >> 16) & 1);
    return (ushort)(u >> 16);
}
// Packed f32 (VOP3P, full-rate 2xFP32 — the 157 TF path)
static __device__ __forceinline__ f32x2 pk_fma(f32x2 a, f32x2 b, f32x2 c) {
    f32x2 d;
    asm("v_pk_fma_f32 %0, %1, %2, %3" : "=v"(d) : "v"(a), "v"(b), "v"(c));
    return d;
}
static __device__ __forceinline__ f32x2 pk_mul(f32x2 a, f32x2 b) {
    f32x2 d;
    asm("v_pk_mul_f32 %0, %1, %2" : "=v"(d) : "v"(a), "v"(b));
    return d;
}

// ---------------------------------------------------------------------------
// Kernel 0 (grid 640):
//   bx <  128: x -> xbs, bf16 PRE-SWIZZLED in MFMA A-fragment order
//   bx in [128,384): W1 -> Bts, bf16 fragment order over n-rows
//   bx >= 384: out = b2 (init for k_score's atomic accumulation)
// ---------------------------------------------------------------------------
__global__ __launch_bounds__(256) void k_convert(const float* __restrict__ x,
                                                 const float* __restrict__ W1,
                                                 const float* __restrict__ b2,
                                                 short* __restrict__ xbs,
                                                 short* __restrict__ Bts,
                                                 float* __restrict__ out) {
    __shared__ float ts[64][65];
    const int t = threadIdx.x;
    const int bx = blockIdx.x;
    if (bx < 128) {                        // xb swizzle: 32768 short8 chunks
        const int q = bx * 256 + t;
        const int g = q >> 10, ktc = (q >> 6) & 15, l = q & 63;
        const int i = g * 16 + (l & 15);
        const int k0 = ktc * 32 + (l >> 4) * 8;
        const float4 v0 = *(const float4*)&x[i * DD + k0];
        const float4 v1 = *(const float4*)&x[i * DD + k0 + 4];
        bf16x8 o;
        o[0] = (short)f2bf(v0.x); o[1] = (short)f2bf(v0.y);
        o[2] = (short)f2bf(v0.z); o[3] = (short)f2bf(v0.w);
        o[4] = (short)f2bf(v1.x); o[5] = (short)f2bf(v1.y);
        o[6] = (short)f2bf(v1.z); o[7] = (short)f2bf(v1.w);
        *(bf16x8*)&xbs[q * 8] = o;
        return;
    }
    if (bx >= 384) {                       // out init: 65536 float4s
        const int f4 = (bx - 384) * 256 + t;
        const float b = b2[0];
        float4 o; o.x = b; o.y = b; o.z = b; o.w = b;
        ((float4*)out)[f4] = o;
        return;
    }
    const int tid = bx - 128;              // 8 k-tiles x 32 n-tiles
    const int k0 = (tid >> 5) * 64;
    const int nglob = (tid & 31) * 64;
    const int off = (nglob >= 1024) ? 512 : 0;
    const int nm = nglob & 1023;
#pragma unroll
    for (int u = 0; u < 4; ++u) {          // load 64(k) x 64(n) f32
        const int f4 = t + u * 256;
        const int r = f4 >> 4, c = (f4 & 15) * 4;
        *(float4*)&ts[r][c] = *(const float4*)&W1[(off + k0 + r) * HH + nm + c];
    }
    __syncthreads();
#pragma unroll
    for (int u = 0; u < 2; ++u) {          // 512 output chunks, frag order
        const int q = u * 256 + t;
        const int lg = q >> 7, lc = (q >> 6) & 1, l = q & 63;
        const int n_loc = lg * 16 + (l & 15);
        const int k_loc = lc * 32 + (l >> 4) * 8;
        bf16x8 o;
#pragma unroll
        for (int j = 0; j < 8; ++j) o[j] = (short)f2bf(ts[k_loc + j][n_loc]);
        const int gg = (nglob >> 4) + lg;
        const int ktc = (k0 >> 5) + lc;
        *(bf16x8*)&Bts[((gg * 16 + ktc) * 64 + l) * 8] = o;
    }
}

// ---------------------------------------------------------------------------
// Kernel 1: Ebf[i][n] (bf16) = exp2(C*(h + (n>=1024? b1[n-1024] : 0))).
// Fragment-order inputs -> every load is base + lane*16B + ktc*1KB (coalesced).
// Wave tile 16i x 32n, block = 4 waves in i. grid (8, 64) = 512 blocks.
// ---------------------------------------------------------------------------
__global__ __launch_bounds__(256) void k_gemm_mfma(const short* __restrict__ xbs,
                                                   const short* __restrict__ Bts,
                                                   const float* __restrict__ b1,
                                                   short* __restrict__ Ebf) {
    const int t = threadIdx.x;
    const int w = t >> 6, l = t & 63;
    const int gi = blockIdx.x * 4 + w;     // i-group (16 rows)
    const int by = blockIdx.y;
    const int gn0 = by * 2;                // two n-groups of 16

    f32x4 acc[2] = {};
    const short* ap  = xbs + gi * 8192 + l * 8;
    const short* bp0 = Bts + (gn0 + 0) * 8192 + l * 8;
    const short* bp1 = Bts + (gn0 + 1) * 8192 + l * 8;
#pragma unroll
    for (int ktc = 0; ktc < 16; ++ktc) {
        const bf16x8 a = *(const bf16x8*)(ap + ktc * 512);
        acc[0] = __builtin_amdgcn_mfma_f32_16x16x32_bf16(a, *(const bf16x8*)(bp0 + ktc * 512), acc[0], 0, 0, 0);
        acc[1] = __builtin_amdgcn_mfma_f32_16x16x32_bf16(a, *(const bf16x8*)(bp1 + ktc * 512), acc[1], 0, 0, 0);
    }
    // C/D map: (reg r, lane l) -> row (l>>4)*4+r, col l&15 (m89-verified)
    const int lm = l & 15;
    const int orow = gi * 16 + (l >> 4) * 4;
    const bool second = (by >= 32);
#pragma unroll
    for (int c = 0; c < 2; ++c) {
        const int n = by * 32 + c * 16 + lm;
        const float badd = second ? b1[n - HH] : 0.0f;
#pragma unroll
        for (int r = 0; r < 4; ++r) {
            Ebf[(orow + r) * (2 * HH) + n] =
                (short)f2bf(exp2_fast(C2LOG2E * (acc[c][r] + badd)));
        }
    }
}

// ---------------------------------------------------------------------------
// Kernel 2: partial scores, atomically accumulated into out.
// z in [0,16): h-range [z*64, +64). bf16 LDS tiles (18 KB -> 8 blocks/CU).
// Inner: per 8h, two 4-way fraction trees in the two lanes of packed-f32
// registers (v_pk_fma_f32/v_pk_mul_f32), one scalar cross-combine + one rcp.
// 42 cyc / 8 elem = 5.25 cyc/elem on the tree (vs 9 scalar).
// ---------------------------------------------------------------------------
__global__ __launch_bounds__(256) void k_score(const short* __restrict__ Ebf,
                                               const float* __restrict__ W2,
                                               float* __restrict__ out) {
    __shared__ short e1s[64][72];   // row stride 144 B (16B-aligned)
    __shared__ short e2s[64][72];
    __shared__ float w2s[64];       // PAIRED layout: per 8h-block q:
                                    // [q*8+2j]=W2[q8+j], [q*8+2j+1]=W2[q8+4+j]
    const int t = threadIdx.x;
    const int i0 = blockIdx.x * 64, j0 = blockIdx.y * 64;
    const int hb = blockIdx.z * 64;
    const int tx = t & 15, ty = t >> 4;

#pragma unroll
    for (int u = 0; u < 2; ++u) {          // stage 64x64 bf16 of E1 and E2
        const int q = u * 256 + t;
        const int r = q >> 3, c8 = (q & 7) * 8;
        *(bf16x8*)&e1s[r][c8] = *(const bf16x8*)&Ebf[(i0 + r) * (2 * HH) + hb + c8];
        *(bf16x8*)&e2s[r][c8] = *(const bf16x8*)&Ebf[(j0 + r) * (2 * HH) + HH + hb + c8];
    }
    if (t < 64) {                          // paired W2 staging
        const int q = t >> 3, r = t & 7;
        const int pos = q * 8 + ((r < 4) ? 2 * r : 2 * (r - 4) + 1);
        w2s[pos] = W2[hb + t];
    }
    __syncthreads();

    float acc[4][4] = {};
    f32x2 swv = {0.0f, 0.0f};
    const f32x2 one2 = {1.0f, 1.0f};
    const int ty4 = ty * 4;
#pragma unroll 1
    for (int q = 0; q < 8; ++q) {          // 8 h per step
        const int h8 = q * 8;
        // unpack rows into (h_j, h_{j+4}) packed pairs: 8 bit-ops per row
        f32x2 ep[4][4], fp[4][4];
#pragma unroll
        for (int m = 0; m < 4; ++m) {
            const int4 v = *(const int4*)&e1s[ty4 + m][h8];
            ep[m][0] = (f32x2){__uint_as_float((unsigned)v.x << 16),
                               __uint_as_float((unsigned)v.z << 16)};
            ep[m][1] = (f32x2){__uint_as_float((unsigned)v.x & 0xFFFF0000u),
                               __uint_as_float((unsigned)v.z & 0xFFFF0000u)};
            ep[m][2] = (f32x2){__uint_as_float((unsigned)v.y << 16),
                               __uint_as_float((unsigned)v.w << 16)};
            ep[m][3] = (f32x2){__uint_as_float((unsigned)v.y & 0xFFFF0000u),
                               __uint_as_float((unsigned)v.w & 0xFFFF0000u)};
        }
#pragma unroll
        for (int n = 0; n < 4; ++n) {
            const int4 v = *(const int4*)&e2s[tx + n * 16][h8];
            fp[n][0] = (f32x2){__uint_as_float((unsigned)v.x << 16),
                               __uint_as_float((unsigned)v.z << 16)};
            fp[n][1] = (f32x2){__uint_as_float((unsigned)v.x & 0xFFFF0000u),
                               __uint_as_float((unsigned)v.z & 0xFFFF0000u)};
            fp[n][2] = (f32x2){__uint_as_float((unsigned)v.y << 16),
                               __uint_as_float((unsigned)v.w << 16)};
            fp[n][3] = (f32x2){__uint_as_float((unsigned)v.y & 0xFFFF0000u),
                               __uint_as_float((unsigned)v.w & 0xFFFF0000u)};
        }
        f32x2 wp[4];
#pragma unroll
        for (int j = 0; j < 4; ++j) wp[j] = *(const f32x2*)&w2s[q * 8 + 2 * j];
        swv += wp[0] + wp[1] + wp[2] + wp[3];

#pragma unroll
        for (int m = 0; m < 4; ++m) {
#pragma unroll
            for (int n = 0; n < 4; ++n) {
                // lane x: h8+0..3 tree; lane y: h8+4..7 tree
                const f32x2 d0 = pk_fma(ep[m][0], fp[n][0], one2);
                const f32x2 d1 = pk_fma(ep[m][1], fp[n][1], one2);
                const f32x2 d2 = pk_fma(ep[m][2], fp[n][2], one2);
                const f32x2 d3 = pk_fma(ep[m][3], fp[n][3], one2);
                const f32x2 d01 = pk_mul(d0, d1);
                const f32x2 d23 = pk_mul(d2, d3);
                const f32x2 n01 = pk_fma(wp[0], d1, pk_mul(wp[1], d0));
                const f32x2 n23 = pk_fma(wp[2], d3, pk_mul(wp[3], d2));
                const f32x2 N4 = pk_fma(n01, d23, pk_mul(n23, d01));
                const f32x2 D4 = pk_mul(d01, d23);
                // 8-way scalar cross-combine
                const float Nn = __builtin_fmaf(N4.x, D4.y, N4.y * D4.x);
                const float Dd = D4.x * D4.y;
                acc[m][n] = __builtin_fmaf(Nn, rcp_fast(Dd), acc[m][n]);
            }
        }
    }

    const float sw = swv.x + swv.y;
#pragma unroll
    for (int m = 0; m < 4; ++m) {
        const int row = i0 + ty4 + m;
#pragma unroll
        for (int n = 0; n < 4; ++n) {
            const int col = j0 + tx + n * 16;
            atomicAdd(&out[row * NN + col], sw - 2.0f * acc[m][n]);
        }
    }
}

extern "C" void kernel_launch(void* const* d_in, const int* in_sizes, int n_in,
                              void* d_out, int out_size, void* d_ws, size_t ws_size,
                              hipStream_t stream) {
    const float* x  = (const float*)d_in[0];
    const float* W1 = (const float*)d_in[1];
    const float* b1 = (const float*)d_in[2];
    const float* W2 = (const float*)d_in[3];
    const float* b2 = (const float*)d_in[4];
    float* out = (float*)d_out;

    short* Ebf = (short*)d_ws;                   // 512*2048 bf16 = 2 MB
    short* xbs = Ebf + NN * 2 * HH;              // 512*512 bf16  = 0.5 MB
    short* Bts = xbs + NN * DD;                  // 2048*512 bf16 = 2 MB

    k_convert<<<dim3(640), 256, 0, stream>>>(x, W1, b2, xbs, Bts, out);
    k_gemm_mfma<<<dim3(8, 64), 256, 0, stream>>>(xbs, Bts, b1, Ebf);
    k_score<<<dim3(8, 8, 16), 256, 0, stream>>>(Ebf, W2, out);
}

// Round 8
// 43.801 us; speedup vs baseline: 1.0506x; 1.0506x over previous
//
#include <hip/hip_runtime.h>
#include <math.h>

#define NN 512
#define DD 512
#define HH 1024
#define C2LOG2E 2.8853900817779268f   // 2*log2(e): exp(2y) = exp2(C*y)

typedef __attribute__((ext_vector_type(8))) short bf16x8;
typedef __attribute__((ext_vector_type(4))) float f32x4;

static __device__ __forceinline__ float rcp_fast(float x) {
    return __builtin_amdgcn_rcpf(x);   // v_rcp_f32
}
static __device__ __forceinline__ float exp2_fast(float x) {
    return __builtin_amdgcn_exp2f(x);  // v_exp_f32
}
static __device__ __forceinline__ ushort f2bf(float f) {   // RNE f32->bf16
    unsigned u = __float_as_uint(f);
    u += 0x7FFF + ((u >> 16) & 1);
    return (ushort)(u >> 16);
}
static __device__ __forceinline__ float bf2f(short u) {    // bf16->f32: 1 shl
    return __uint_as_float(((unsigned)(ushort)u) << 16);
}

// ---------------------------------------------------------------------------
// Kernel 0 (grid 640):
//   bx <  128: x -> xbs, bf16 PRE-SWIZZLED in MFMA A-fragment order
//   bx in [128,384): W1 -> Bts, bf16 fragment order over n-rows
//   bx >= 384: out = b2 (init for k_score's atomic accumulation)
// ---------------------------------------------------------------------------
__global__ __launch_bounds__(256) void k_convert(const float* __restrict__ x,
                                                 const float* __restrict__ W1,
                                                 const float* __restrict__ b2,
                                                 short* __restrict__ xbs,
                                                 short* __restrict__ Bts,
                                                 float* __restrict__ out) {
    __shared__ float ts[64][65];
    const int t = threadIdx.x;
    const int bx = blockIdx.x;
    if (bx < 128) {                        // xb swizzle: 32768 short8 chunks
        const int q = bx * 256 + t;
        const int g = q >> 10, ktc = (q >> 6) & 15, l = q & 63;
        const int i = g * 16 + (l & 15);
        const int k0 = ktc * 32 + (l >> 4) * 8;
        const float4 v0 = *(const float4*)&x[i * DD + k0];
        const float4 v1 = *(const float4*)&x[i * DD + k0 + 4];
        bf16x8 o;
        o[0] = (short)f2bf(v0.x); o[1] = (short)f2bf(v0.y);
        o[2] = (short)f2bf(v0.z); o[3] = (short)f2bf(v0.w);
        o[4] = (short)f2bf(v1.x); o[5] = (short)f2bf(v1.y);
        o[6] = (short)f2bf(v1.z); o[7] = (short)f2bf(v1.w);
        *(bf16x8*)&xbs[q * 8] = o;
        return;
    }
    if (bx >= 384) {                       // out init: 65536 float4s
        const int f4 = (bx - 384) * 256 + t;
        const float b = b2[0];
        float4 o; o.x = b; o.y = b; o.z = b; o.w = b;
        ((float4*)out)[f4] = o;
        return;
    }
    const int tid = bx - 128;              // 8 k-tiles x 32 n-tiles
    const int k0 = (tid >> 5) * 64;
    const int nglob = (tid & 31) * 64;
    const int off = (nglob >= 1024) ? 512 : 0;
    const int nm = nglob & 1023;
#pragma unroll
    for (int u = 0; u < 4; ++u) {          // load 64(k) x 64(n) f32
        const int f4 = t + u * 256;
        const int r = f4 >> 4, c = (f4 & 15) * 4;
        *(float4*)&ts[r][c] = *(const float4*)&W1[(off + k0 + r) * HH + nm + c];
    }
    __syncthreads();
#pragma unroll
    for (int u = 0; u < 2; ++u) {          // 512 output chunks, frag order
        const int q = u * 256 + t;
        const int lg = q >> 7, lc = (q >> 6) & 1, l = q & 63;
        const int n_loc = lg * 16 + (l & 15);
        const int k_loc = lc * 32 + (l >> 4) * 8;
        bf16x8 o;
#pragma unroll
        for (int j = 0; j < 8; ++j) o[j] = (short)f2bf(ts[k_loc + j][n_loc]);
        const int gg = (nglob >> 4) + lg;
        const int ktc = (k0 >> 5) + lc;
        *(bf16x8*)&Bts[((gg * 16 + ktc) * 64 + l) * 8] = o;
    }
}

// ---------------------------------------------------------------------------
// Kernel 1: Ebf[i][n] (bf16) = exp2(C*(h + (n>=1024? b1[n-1024] : 0))).
// Fragment-order inputs -> every load is base + lane*16B + ktc*1KB (coalesced).
// Wave tile 16i x 32n, block = 4 waves in i. grid (8, 64) = 512 blocks.
// ---------------------------------------------------------------------------
__global__ __launch_bounds__(256) void k_gemm_mfma(const short* __restrict__ xbs,
                                                   const short* __restrict__ Bts,
                                                   const float* __restrict__ b1,
                                                   short* __restrict__ Ebf) {
    const int t = threadIdx.x;
    const int w = t >> 6, l = t & 63;
    const int gi = blockIdx.x * 4 + w;     // i-group (16 rows)
    const int by = blockIdx.y;
    const int gn0 = by * 2;                // two n-groups of 16

    f32x4 acc[2] = {};
    const short* ap  = xbs + gi * 8192 + l * 8;
    const short* bp0 = Bts + (gn0 + 0) * 8192 + l * 8;
    const short* bp1 = Bts + (gn0 + 1) * 8192 + l * 8;
#pragma unroll
    for (int ktc = 0; ktc < 16; ++ktc) {
        const bf16x8 a = *(const bf16x8*)(ap + ktc * 512);
        acc[0] = __builtin_amdgcn_mfma_f32_16x16x32_bf16(a, *(const bf16x8*)(bp0 + ktc * 512), acc[0], 0, 0, 0);
        acc[1] = __builtin_amdgcn_mfma_f32_16x16x32_bf16(a, *(const bf16x8*)(bp1 + ktc * 512), acc[1], 0, 0, 0);
    }
    // C/D map: (reg r, lane l) -> row (l>>4)*4+r, col l&15 (m89-verified)
    const int lm = l & 15;
    const int orow = gi * 16 + (l >> 4) * 4;
    const bool second = (by >= 32);
#pragma unroll
    for (int c = 0; c < 2; ++c) {
        const int n = by * 32 + c * 16 + lm;
        const float badd = second ? b1[n - HH] : 0.0f;
#pragma unroll
        for (int r = 0; r < 4; ++r) {
            Ebf[(orow + r) * (2 * HH) + n] =
                (short)f2bf(exp2_fast(C2LOG2E * (acc[c][r] + badd)));
        }
    }
}

// ---------------------------------------------------------------------------
// Kernel 2: partial scores, atomically accumulated into out.
// z in [0,8): h-range [z*128, +128) staged in ONE shot (35 KB LDS, 1 barrier).
// out[i][j] += sum_h W2[h] - 2*sum_h W2[h]/(1 + E1[i][h]*E2[j][h])
// 64x64 tile, 256 thr, 4x4 micro. Per 8h: two scalar 4-way fraction trees +
// cross-combine -> ONE v_rcp per 8 h. grid (8, 8, 8) = 512 blocks.
// Atomics: 512^2 * 8 = 2.1M (halved vs z=16).
// ---------------------------------------------------------------------------
__global__ __launch_bounds__(256) void k_score(const short* __restrict__ Ebf,
                                               const float* __restrict__ W2,
                                               float* __restrict__ out) {
    __shared__ short e1s[64][136];  // 64 rows x 128h + 8 pad (row 272 B)
    __shared__ short e2s[64][136];
    __shared__ float w2s[128];
    const int t = threadIdx.x;
    const int i0 = blockIdx.x * 64, j0 = blockIdx.y * 64;
    const int hb = blockIdx.z * 128;
    const int tx = t & 15, ty = t >> 4;

#pragma unroll
    for (int u = 0; u < 4; ++u) {          // stage 64x128 bf16 of E1 and E2
        const int q = u * 256 + t;
        const int r = q >> 4, c8 = (q & 15) * 8;
        *(bf16x8*)&e1s[r][c8] = *(const bf16x8*)&Ebf[(i0 + r) * (2 * HH) + hb + c8];
        *(bf16x8*)&e2s[r][c8] = *(const bf16x8*)&Ebf[(j0 + r) * (2 * HH) + HH + hb + c8];
    }
    if (t < 128) w2s[t] = W2[hb + t];
    __syncthreads();

    float acc[4][4] = {};
    float sw = 0.0f;
    const int ty4 = ty * 4;
#pragma unroll 2
    for (int s = 0; s < 16; ++s) {         // 8 h per step
        const int h8 = s * 8;
        float ef[4][8], ff[4][8];
#pragma unroll
        for (int m = 0; m < 4; ++m) {
            const bf16x8 v = *(const bf16x8*)&e1s[ty4 + m][h8];
#pragma unroll
            for (int j = 0; j < 8; ++j) ef[m][j] = bf2f(v[j]);
        }
#pragma unroll
        for (int n = 0; n < 4; ++n) {
            const bf16x8 v = *(const bf16x8*)&e2s[tx + n * 16][h8];
#pragma unroll
            for (int j = 0; j < 8; ++j) ff[n][j] = bf2f(v[j]);
        }
        const float4 wl = *(const float4*)&w2s[h8];
        const float4 wh = *(const float4*)&w2s[h8 + 4];
#pragma unroll
        for (int m = 0; m < 4; ++m) {
#pragma unroll
            for (int n = 0; n < 4; ++n) {
                const float* em = ef[m];
                const float* fn = ff[n];
                const float d0 = __builtin_fmaf(em[0], fn[0], 1.0f);
                const float d1 = __builtin_fmaf(em[1], fn[1], 1.0f);
                const float d2 = __builtin_fmaf(em[2], fn[2], 1.0f);
                const float d3 = __builtin_fmaf(em[3], fn[3], 1.0f);
                const float d4 = __builtin_fmaf(em[4], fn[4], 1.0f);
                const float d5 = __builtin_fmaf(em[5], fn[5], 1.0f);
                const float d6 = __builtin_fmaf(em[6], fn[6], 1.0f);
                const float d7 = __builtin_fmaf(em[7], fn[7], 1.0f);
                const float d01 = d0 * d1, d23 = d2 * d3;
                const float d45 = d4 * d5, d67 = d6 * d7;
                const float n01 = __builtin_fmaf(wl.x, d1, wl.y * d0);
                const float n23 = __builtin_fmaf(wl.z, d3, wl.w * d2);
                const float n45 = __builtin_fmaf(wh.x, d5, wh.y * d4);
                const float n67 = __builtin_fmaf(wh.z, d7, wh.w * d6);
                const float N1 = __builtin_fmaf(n01, d23, n23 * d01);
                const float N2 = __builtin_fmaf(n45, d67, n67 * d45);
                const float D1 = d01 * d23, D2 = d45 * d67;
                // cross-combine: one rcp per 8 h (D2 <= e^64, f32-safe)
                const float Nn = __builtin_fmaf(N1, D2, N2 * D1);
                const float Dd = D1 * D2;
                acc[m][n] = __builtin_fmaf(Nn, rcp_fast(Dd), acc[m][n]);
            }
        }
        sw += wl.x + wl.y + wl.z + wl.w + wh.x + wh.y + wh.z + wh.w;
    }

#pragma unroll
    for (int m = 0; m < 4; ++m) {
        const int row = i0 + ty4 + m;
#pragma unroll
        for (int n = 0; n < 4; ++n) {
            const int col = j0 + tx + n * 16;
            atomicAdd(&out[row * NN + col], sw - 2.0f * acc[m][n]);
        }
    }
}

extern "C" void kernel_launch(void* const* d_in, const int* in_sizes, int n_in,
                              void* d_out, int out_size, void* d_ws, size_t ws_size,
                              hipStream_t stream) {
    const float* x  = (const float*)d_in[0];
    const float* W1 = (const float*)d_in[1];
    const float* b1 = (const float*)d_in[2];
    const float* W2 = (const float*)d_in[3];
    const float* b2 = (const float*)d_in[4];
    float* out = (float*)d_out;

    short* Ebf = (short*)d_ws;                   // 512*2048 bf16 = 2 MB
    short* xbs = Ebf + NN * 2 * HH;              // 512*512 bf16  = 0.5 MB
    short* Bts = xbs + NN * DD;                  // 2048*512 bf16 = 2 MB

    k_convert<<<dim3(640), 256, 0, stream>>>(x, W1, b2, xbs, Bts, out);
    k_gemm_mfma<<<dim3(8, 64), 256, 0, stream>>>(xbs, Bts, b1, Ebf);
    k_score<<<dim3(8, 8, 8), 256, 0, stream>>>(Ebf, W2, out);
}

// Round 9
// 42.664 us; speedup vs baseline: 1.0786x; 1.0267x over previous
//
#include <hip/hip_runtime.h>
#include <math.h>

#define NN 512
#define DD 512
#define HH 1024
#define C2LOG2E 2.8853900817779268f   // 2*log2(e): exp(2y) = exp2(C*y)

typedef __attribute__((ext_vector_type(8))) short bf16x8;
typedef __attribute__((ext_vector_type(4))) float f32x4;

static __device__ __forceinline__ float rcp_fast(float x) {
    return __builtin_amdgcn_rcpf(x);   // v_rcp_f32
}
static __device__ __forceinline__ float exp2_fast(float x) {
    return __builtin_amdgcn_exp2f(x);  // v_exp_f32
}
static __device__ __forceinline__ ushort f2bf(float f) {   // RNE f32->bf16
    unsigned u = __float_as_uint(f);
    u += 0x7FFF + ((u >> 16) & 1);
    return (ushort)(u >> 16);
}
static __device__ __forceinline__ float bf2f(short u) {    // bf16->f32: 1 shl
    return __uint_as_float(((unsigned)(ushort)u) << 16);
}

// ---------------------------------------------------------------------------
// Kernel 0 (grid 640):
//   bx <  128: x -> xbs, bf16 PRE-SWIZZLED in MFMA A-fragment order
//   bx in [128,384): W1 -> Bts, bf16 fragment order over n-rows
//   bx >= 384: out = b2 (init for k_score's atomic accumulation)
// ---------------------------------------------------------------------------
__global__ __launch_bounds__(256) void k_convert(const float* __restrict__ x,
                                                 const float* __restrict__ W1,
                                                 const float* __restrict__ b2,
                                                 short* __restrict__ xbs,
                                                 short* __restrict__ Bts,
                                                 float* __restrict__ out) {
    __shared__ float ts[64][65];
    const int t = threadIdx.x;
    const int bx = blockIdx.x;
    if (bx < 128) {                        // xb swizzle: 32768 short8 chunks
        const int q = bx * 256 + t;
        const int g = q >> 10, ktc = (q >> 6) & 15, l = q & 63;
        const int i = g * 16 + (l & 15);
        const int k0 = ktc * 32 + (l >> 4) * 8;
        const float4 v0 = *(const float4*)&x[i * DD + k0];
        const float4 v1 = *(const float4*)&x[i * DD + k0 + 4];
        bf16x8 o;
        o[0] = (short)f2bf(v0.x); o[1] = (short)f2bf(v0.y);
        o[2] = (short)f2bf(v0.z); o[3] = (short)f2bf(v0.w);
        o[4] = (short)f2bf(v1.x); o[5] = (short)f2bf(v1.y);
        o[6] = (short)f2bf(v1.z); o[7] = (short)f2bf(v1.w);
        *(bf16x8*)&xbs[q * 8] = o;
        return;
    }
    if (bx >= 384) {                       // out init: 65536 float4s
        const int f4 = (bx - 384) * 256 + t;
        const float b = b2[0];
        float4 o; o.x = b; o.y = b; o.z = b; o.w = b;
        ((float4*)out)[f4] = o;
        return;
    }
    const int tid = bx - 128;              // 8 k-tiles x 32 n-tiles
    const int k0 = (tid >> 5) * 64;
    const int nglob = (tid & 31) * 64;
    const int off = (nglob >= 1024) ? 512 : 0;
    const int nm = nglob & 1023;
#pragma unroll
    for (int u = 0; u < 4; ++u) {          // load 64(k) x 64(n) f32
        const int f4 = t + u * 256;
        const int r = f4 >> 4, c = (f4 & 15) * 4;
        *(float4*)&ts[r][c] = *(const float4*)&W1[(off + k0 + r) * HH + nm + c];
    }
    __syncthreads();
#pragma unroll
    for (int u = 0; u < 2; ++u) {          // 512 output chunks, frag order
        const int q = u * 256 + t;
        const int lg = q >> 7, lc = (q >> 6) & 1, l = q & 63;
        const int n_loc = lg * 16 + (l & 15);
        const int k_loc = lc * 32 + (l >> 4) * 8;
        bf16x8 o;
#pragma unroll
        for (int j = 0; j < 8; ++j) o[j] = (short)f2bf(ts[k_loc + j][n_loc]);
        const int gg = (nglob >> 4) + lg;
        const int ktc = (k0 >> 5) + lc;
        *(bf16x8*)&Bts[((gg * 16 + ktc) * 64 + l) * 8] = o;
    }
}

// ---------------------------------------------------------------------------
// Kernel 1: Ebf[i][n] (bf16) = exp2(C*(h + (n>=1024? b1[n-1024] : 0))).
// Fragment-order inputs -> every load is base + lane*16B + ktc*1KB (coalesced).
// Wave tile 16i x 32n, block = 4 waves in i. grid (8, 64) = 512 blocks.
// ---------------------------------------------------------------------------
__global__ __launch_bounds__(256) void k_gemm_mfma(const short* __restrict__ xbs,
                                                   const short* __restrict__ Bts,
                                                   const float* __restrict__ b1,
                                                   short* __restrict__ Ebf) {
    const int t = threadIdx.x;
    const int w = t >> 6, l = t & 63;
    const int gi = blockIdx.x * 4 + w;     // i-group (16 rows)
    const int by = blockIdx.y;
    const int gn0 = by * 2;                // two n-groups of 16

    f32x4 acc[2] = {};
    const short* ap  = xbs + gi * 8192 + l * 8;
    const short* bp0 = Bts + (gn0 + 0) * 8192 + l * 8;
    const short* bp1 = Bts + (gn0 + 1) * 8192 + l * 8;
#pragma unroll
    for (int ktc = 0; ktc < 16; ++ktc) {
        const bf16x8 a = *(const bf16x8*)(ap + ktc * 512);
        acc[0] = __builtin_amdgcn_mfma_f32_16x16x32_bf16(a, *(const bf16x8*)(bp0 + ktc * 512), acc[0], 0, 0, 0);
        acc[1] = __builtin_amdgcn_mfma_f32_16x16x32_bf16(a, *(const bf16x8*)(bp1 + ktc * 512), acc[1], 0, 0, 0);
    }
    // C/D map: (reg r, lane l) -> row (l>>4)*4+r, col l&15 (m89-verified)
    const int lm = l & 15;
    const int orow = gi * 16 + (l >> 4) * 4;
    const bool second = (by >= 32);
#pragma unroll
    for (int c = 0; c < 2; ++c) {
        const int n = by * 32 + c * 16 + lm;
        const float badd = second ? b1[n - HH] : 0.0f;
#pragma unroll
        for (int r = 0; r < 4; ++r) {
            Ebf[(orow + r) * (2 * HH) + n] =
                (short)f2bf(exp2_fast(C2LOG2E * (acc[c][r] + badd)));
        }
    }
}

// ---------------------------------------------------------------------------
// Kernel 2: partial scores, atomically accumulated into out.
// z in [0,16): h-range [z*64, +64). bf16 LDS (16.5 KB -> LDS allows 8 bl/CU;
// VGPR-capped ~4). 64x64 tile, 256 thr, 4x4 micro. Per 8h: two 4-way fraction
// trees + scalar cross-combine -> ONE v_rcp per 8 h. grid (8, 8, 16) = 1024.
// ---------------------------------------------------------------------------
__global__ __launch_bounds__(256) void k_score(const short* __restrict__ Ebf,
                                               const float* __restrict__ W2,
                                               float* __restrict__ out) {
    __shared__ short e1s[64][72];   // stride 36 dwords == 4 mod 32: 2-way max
    __shared__ short e2s[64][72];
    __shared__ float w2s[64];
    const int t = threadIdx.x;
    const int i0 = blockIdx.x * 64, j0 = blockIdx.y * 64;
    const int hb = blockIdx.z * 64;
    const int tx = t & 15, ty = t >> 4;

#pragma unroll
    for (int u = 0; u < 2; ++u) {          // stage 64x64 bf16 of E1 and E2
        const int q = u * 256 + t;
        const int r = q >> 3, c8 = (q & 7) * 8;
        *(bf16x8*)&e1s[r][c8] = *(const bf16x8*)&Ebf[(i0 + r) * (2 * HH) + hb + c8];
        *(bf16x8*)&e2s[r][c8] = *(const bf16x8*)&Ebf[(j0 + r) * (2 * HH) + HH + hb + c8];
    }
    if (t < 64) w2s[t] = W2[hb + t];
    __syncthreads();

    float acc[4][4] = {};
    float sw = 0.0f;
    const int ty4 = ty * 4;
#pragma unroll 2
    for (int s = 0; s < 8; ++s) {          // 8 h per step
        const int h8 = s * 8;
        float ef[4][8], ff[4][8];
#pragma unroll
        for (int m = 0; m < 4; ++m) {
            const bf16x8 v = *(const bf16x8*)&e1s[ty4 + m][h8];
#pragma unroll
            for (int j = 0; j < 8; ++j) ef[m][j] = bf2f(v[j]);
        }
#pragma unroll
        for (int n = 0; n < 4; ++n) {
            const bf16x8 v = *(const bf16x8*)&e2s[tx + n * 16][h8];
#pragma unroll
            for (int j = 0; j < 8; ++j) ff[n][j] = bf2f(v[j]);
        }
        const float4 wl = *(const float4*)&w2s[h8];
        const float4 wh = *(const float4*)&w2s[h8 + 4];
#pragma unroll
        for (int m = 0; m < 4; ++m) {
#pragma unroll
            for (int n = 0; n < 4; ++n) {
                const float* em = ef[m];
                const float* fn = ff[n];
                const float d0 = __builtin_fmaf(em[0], fn[0], 1.0f);
                const float d1 = __builtin_fmaf(em[1], fn[1], 1.0f);
                const float d2 = __builtin_fmaf(em[2], fn[2], 1.0f);
                const float d3 = __builtin_fmaf(em[3], fn[3], 1.0f);
                const float d4 = __builtin_fmaf(em[4], fn[4], 1.0f);
                const float d5 = __builtin_fmaf(em[5], fn[5], 1.0f);
                const float d6 = __builtin_fmaf(em[6], fn[6], 1.0f);
                const float d7 = __builtin_fmaf(em[7], fn[7], 1.0f);
                const float d01 = d0 * d1, d23 = d2 * d3;
                const float d45 = d4 * d5, d67 = d6 * d7;
                const float n01 = __builtin_fmaf(wl.x, d1, wl.y * d0);
                const float n23 = __builtin_fmaf(wl.z, d3, wl.w * d2);
                const float n45 = __builtin_fmaf(wh.x, d5, wh.y * d4);
                const float n67 = __builtin_fmaf(wh.z, d7, wh.w * d6);
                const float N1 = __builtin_fmaf(n01, d23, n23 * d01);
                const float N2 = __builtin_fmaf(n45, d67, n67 * d45);
                const float D1 = d01 * d23, D2 = d45 * d67;
                // cross-combine: one rcp per 8 h (D <= e^64, f32-safe)
                const float Nn = __builtin_fmaf(N1, D2, N2 * D1);
                const float Dd = D1 * D2;
                acc[m][n] = __builtin_fmaf(Nn, rcp_fast(Dd), acc[m][n]);
            }
        }
        sw += wl.x + wl.y + wl.z + wl.w + wh.x + wh.y + wh.z + wh.w;
    }

#pragma unroll
    for (int m = 0; m < 4; ++m) {
        const int row = i0 + ty4 + m;
#pragma unroll
        for (int n = 0; n < 4; ++n) {
            const int col = j0 + tx + n * 16;
            atomicAdd(&out[row * NN + col], sw - 2.0f * acc[m][n]);
        }
    }
}

extern "C" void kernel_launch(void* const* d_in, const int* in_sizes, int n_in,
                              void* d_out, int out_size, void* d_ws, size_t ws_size,
                              hipStream_t stream) {
    const float* x  = (const float*)d_in[0];
    const float* W1 = (const float*)d_in[1];
    const float* b1 = (const float*)d_in[2];
    const float* W2 = (const float*)d_in[3];
    const float* b2 = (const float*)d_in[4];
    float* out = (float*)d_out;

    short* Ebf = (short*)d_ws;                   // 512*2048 bf16 = 2 MB
    short* xbs = Ebf + NN * 2 * HH;              // 512*512 bf16  = 0.5 MB
    short* Bts = xbs + NN * DD;                  // 2048*512 bf16 = 2 MB

    k_convert<<<dim3(640), 256, 0, stream>>>(x, W1, b2, xbs, Bts, out);
    k_gemm_mfma<<<dim3(8, 64), 256, 0, stream>>>(xbs, Bts, b1, Ebf);
    k_score<<<dim3(8, 8, 16), 256, 0, stream>>>(Ebf, W2, out);
}

// Round 10
// 42.341 us; speedup vs baseline: 1.0869x; 1.0076x over previous
//
#include <hip/hip_runtime.h>
#include <math.h>

#define NN 512
#define DD 512
#define HH 1024
#define C2LOG2E 2.8853900817779268f   // 2*log2(e): exp(2y) = exp2(C*y)

typedef __attribute__((ext_vector_type(8))) short bf16x8;
typedef __attribute__((ext_vector_type(4))) float f32x4;

static __device__ __forceinline__ float rcp_fast(float x) {
    return __builtin_amdgcn_rcpf(x);   // v_rcp_f32
}
static __device__ __forceinline__ float exp2_fast(float x) {
    return __builtin_amdgcn_exp2f(x);  // v_exp_f32
}
static __device__ __forceinline__ ushort f2bf(float f) {   // RNE f32->bf16
    unsigned u = __float_as_uint(f);
    u += 0x7FFF + ((u >> 16) & 1);
    return (ushort)(u >> 16);
}
static __device__ __forceinline__ float bf2f(short u) {    // bf16->f32: 1 shl
    return __uint_as_float(((unsigned)(ushort)u) << 16);
}

// ---------------------------------------------------------------------------
// Kernel 0 (grid 640):
//   bx <  128: x -> xbs, bf16 PRE-SWIZZLED in MFMA A-fragment order
//   bx in [128,384): W1 -> Bts, bf16 fragment order over n-rows
//   bx >= 384: out = b2 (init for k_score's atomic accumulation)
// ---------------------------------------------------------------------------
__global__ __launch_bounds__(256) void k_convert(const float* __restrict__ x,
                                                 const float* __restrict__ W1,
                                                 const float* __restrict__ b2,
                                                 short* __restrict__ xbs,
                                                 short* __restrict__ Bts,
                                                 float* __restrict__ out) {
    __shared__ float ts[64][65];
    const int t = threadIdx.x;
    const int bx = blockIdx.x;
    if (bx < 128) {                        // xb swizzle: 32768 short8 chunks
        const int q = bx * 256 + t;
        const int g = q >> 10, ktc = (q >> 6) & 15, l = q & 63;
        const int i = g * 16 + (l & 15);
        const int k0 = ktc * 32 + (l >> 4) * 8;
        const float4 v0 = *(const float4*)&x[i * DD + k0];
        const float4 v1 = *(const float4*)&x[i * DD + k0 + 4];
        bf16x8 o;
        o[0] = (short)f2bf(v0.x); o[1] = (short)f2bf(v0.y);
        o[2] = (short)f2bf(v0.z); o[3] = (short)f2bf(v0.w);
        o[4] = (short)f2bf(v1.x); o[5] = (short)f2bf(v1.y);
        o[6] = (short)f2bf(v1.z); o[7] = (short)f2bf(v1.w);
        *(bf16x8*)&xbs[q * 8] = o;
        return;
    }
    if (bx >= 384) {                       // out init: 65536 float4s
        const int f4 = (bx - 384) * 256 + t;
        const float b = b2[0];
        float4 o; o.x = b; o.y = b; o.z = b; o.w = b;
        ((float4*)out)[f4] = o;
        return;
    }
    const int tid = bx - 128;              // 8 k-tiles x 32 n-tiles
    const int k0 = (tid >> 5) * 64;
    const int nglob = (tid & 31) * 64;
    const int off = (nglob >= 1024) ? 512 : 0;
    const int nm = nglob & 1023;
#pragma unroll
    for (int u = 0; u < 4; ++u) {          // load 64(k) x 64(n) f32
        const int f4 = t + u * 256;
        const int r = f4 >> 4, c = (f4 & 15) * 4;
        *(float4*)&ts[r][c] = *(const float4*)&W1[(off + k0 + r) * HH + nm + c];
    }
    __syncthreads();
#pragma unroll
    for (int u = 0; u < 2; ++u) {          // 512 output chunks, frag order
        const int q = u * 256 + t;
        const int lg = q >> 7, lc = (q >> 6) & 1, l = q & 63;
        const int n_loc = lg * 16 + (l & 15);
        const int k_loc = lc * 32 + (l >> 4) * 8;
        bf16x8 o;
#pragma unroll
        for (int j = 0; j < 8; ++j) o[j] = (short)f2bf(ts[k_loc + j][n_loc]);
        const int gg = (nglob >> 4) + lg;
        const int ktc = (k0 >> 5) + lc;
        *(bf16x8*)&Bts[((gg * 16 + ktc) * 64 + l) * 8] = o;
    }
}

// ---------------------------------------------------------------------------
// Kernel 1: Ebf[i][n] (bf16) = exp2(C*(h + (n>=1024? b1[n-1024] : 0))).
// Fragment-order inputs -> every load is base + lane*16B + ktc*1KB (coalesced).
// Wave tile 16i x 32n, block = 4 waves in i. grid (8, 64) = 512 blocks.
// ---------------------------------------------------------------------------
__global__ __launch_bounds__(256) void k_gemm_mfma(const short* __restrict__ xbs,
                                                   const short* __restrict__ Bts,
                                                   const float* __restrict__ b1,
                                                   short* __restrict__ Ebf) {
    const int t = threadIdx.x;
    const int w = t >> 6, l = t & 63;
    const int gi = blockIdx.x * 4 + w;     // i-group (16 rows)
    const int by = blockIdx.y;
    const int gn0 = by * 2;                // two n-groups of 16

    f32x4 acc[2] = {};
    const short* ap  = xbs + gi * 8192 + l * 8;
    const short* bp0 = Bts + (gn0 + 0) * 8192 + l * 8;
    const short* bp1 = Bts + (gn0 + 1) * 8192 + l * 8;
#pragma unroll
    for (int ktc = 0; ktc < 16; ++ktc) {
        const bf16x8 a = *(const bf16x8*)(ap + ktc * 512);
        acc[0] = __builtin_amdgcn_mfma_f32_16x16x32_bf16(a, *(const bf16x8*)(bp0 + ktc * 512), acc[0], 0, 0, 0);
        acc[1] = __builtin_amdgcn_mfma_f32_16x16x32_bf16(a, *(const bf16x8*)(bp1 + ktc * 512), acc[1], 0, 0, 0);
    }
    // C/D map: (reg r, lane l) -> row (l>>4)*4+r, col l&15 (m89-verified)
    const int lm = l & 15;
    const int orow = gi * 16 + (l >> 4) * 4;
    const bool second = (by >= 32);
#pragma unroll
    for (int c = 0; c < 2; ++c) {
        const int n = by * 32 + c * 16 + lm;
        const float badd = second ? b1[n - HH] : 0.0f;
#pragma unroll
        for (int r = 0; r < 4; ++r) {
            Ebf[(orow + r) * (2 * HH) + n] =
                (short)f2bf(exp2_fast(C2LOG2E * (acc[c][r] + badd)));
        }
    }
}

// ---------------------------------------------------------------------------
// Kernel 2: partial scores, atomically accumulated into out.
// OCCUPANCY RESTRUCTURE: 64(i) x 32(j) tile, 4x2 micro (8 accs) -> VGPR ~90,
// LDS 14 KB, grid (8, 16, 16) = 2048 blocks -> 7-8 blocks/CU resident
// (thread-slot-capped) vs previous ~4. Per 8h: two 4-way fraction trees +
// cross-combine -> ONE v_rcp per 8 h.
// ---------------------------------------------------------------------------
__global__ __launch_bounds__(256) void k_score(const short* __restrict__ Ebf,
                                               const float* __restrict__ W2,
                                               float* __restrict__ out) {
    __shared__ short e1s[64][72];   // stride 36 dwords == 4 mod 32: 2-way max
    __shared__ short e2s[32][72];
    __shared__ float w2s[64];
    const int t = threadIdx.x;
    const int i0 = blockIdx.x * 64, j0 = blockIdx.y * 32;
    const int hb = blockIdx.z * 64;
    const int tx = t & 15, ty = t >> 4;

#pragma unroll
    for (int u = 0; u < 2; ++u) {          // stage E1 64x64 bf16
        const int q = u * 256 + t;
        const int r = q >> 3, c8 = (q & 7) * 8;
        *(bf16x8*)&e1s[r][c8] = *(const bf16x8*)&Ebf[(i0 + r) * (2 * HH) + hb + c8];
    }
    {                                      // stage E2 32x64 bf16
        const int r = t >> 3, c8 = (t & 7) * 8;
        *(bf16x8*)&e2s[r][c8] = *(const bf16x8*)&Ebf[(j0 + r) * (2 * HH) + HH + hb + c8];
    }
    if (t < 64) w2s[t] = W2[hb + t];
    __syncthreads();

    float acc[4][2] = {};
    float sw = 0.0f;
    const int ty4 = ty * 4;
#pragma unroll 2
    for (int s = 0; s < 8; ++s) {          // 8 h per step
        const int h8 = s * 8;
        float ef[4][8], ff[2][8];
#pragma unroll
        for (int m = 0; m < 4; ++m) {
            const bf16x8 v = *(const bf16x8*)&e1s[ty4 + m][h8];
#pragma unroll
            for (int j = 0; j < 8; ++j) ef[m][j] = bf2f(v[j]);
        }
#pragma unroll
        for (int n = 0; n < 2; ++n) {
            const bf16x8 v = *(const bf16x8*)&e2s[tx + n * 16][h8];
#pragma unroll
            for (int j = 0; j < 8; ++j) ff[n][j] = bf2f(v[j]);
        }
        const float4 wl = *(const float4*)&w2s[h8];
        const float4 wh = *(const float4*)&w2s[h8 + 4];
#pragma unroll
        for (int m = 0; m < 4; ++m) {
#pragma unroll
            for (int n = 0; n < 2; ++n) {
                const float* em = ef[m];
                const float* fn = ff[n];
                const float d0 = __builtin_fmaf(em[0], fn[0], 1.0f);
                const float d1 = __builtin_fmaf(em[1], fn[1], 1.0f);
                const float d2 = __builtin_fmaf(em[2], fn[2], 1.0f);
                const float d3 = __builtin_fmaf(em[3], fn[3], 1.0f);
                const float d4 = __builtin_fmaf(em[4], fn[4], 1.0f);
                const float d5 = __builtin_fmaf(em[5], fn[5], 1.0f);
                const float d6 = __builtin_fmaf(em[6], fn[6], 1.0f);
                const float d7 = __builtin_fmaf(em[7], fn[7], 1.0f);
                const float d01 = d0 * d1, d23 = d2 * d3;
                const float d45 = d4 * d5, d67 = d6 * d7;
                const float n01 = __builtin_fmaf(wl.x, d1, wl.y * d0);
                const float n23 = __builtin_fmaf(wl.z, d3, wl.w * d2);
                const float n45 = __builtin_fmaf(wh.x, d5, wh.y * d4);
                const float n67 = __builtin_fmaf(wh.z, d7, wh.w * d6);
                const float N1 = __builtin_fmaf(n01, d23, n23 * d01);
                const float N2 = __builtin_fmaf(n45, d67, n67 * d45);
                const float D1 = d01 * d23, D2 = d45 * d67;
                // cross-combine: one rcp per 8 h (D <= e^64, f32-safe)
                const float Nn = __builtin_fmaf(N1, D2, N2 * D1);
                const float Dd = D1 * D2;
                acc[m][n] = __builtin_fmaf(Nn, rcp_fast(Dd), acc[m][n]);
            }
        }
        sw += wl.x + wl.y + wl.z + wl.w + wh.x + wh.y + wh.z + wh.w;
    }

#pragma unroll
    for (int m = 0; m < 4; ++m) {
        const int row = i0 + ty4 + m;
#pragma unroll
        for (int n = 0; n < 2; ++n) {
            const int col = j0 + tx + n * 16;
            atomicAdd(&out[row * NN + col], sw - 2.0f * acc[m][n]);
        }
    }
}

extern "C" void kernel_launch(void* const* d_in, const int* in_sizes, int n_in,
                              void* d_out, int out_size, void* d_ws, size_t ws_size,
                              hipStream_t stream) {
    const float* x  = (const float*)d_in[0];
    const float* W1 = (const float*)d_in[1];
    const float* b1 = (const float*)d_in[2];
    const float* W2 = (const float*)d_in[3];
    const float* b2 = (const float*)d_in[4];
    float* out = (float*)d_out;

    short* Ebf = (short*)d_ws;                   // 512*2048 bf16 = 2 MB
    short* xbs = Ebf + NN * 2 * HH;              // 512*512 bf16  = 0.5 MB
    short* Bts = xbs + NN * DD;                  // 2048*512 bf16 = 2 MB

    k_convert<<<dim3(640), 256, 0, stream>>>(x, W1, b2, xbs, Bts, out);
    k_gemm_mfma<<<dim3(8, 64), 256, 0, stream>>>(xbs, Bts, b1, Ebf);
    k_score<<<dim3(8, 16, 16), 256, 0, stream>>>(Ebf, W2, out);
}